// Round 5
// baseline (1169.601 us; speedup 1.0000x reference)
//
#include <hip/hip_runtime.h>
#include <hip/hip_bf16.h>
#include <math.h>

typedef unsigned short u16;

#define BATCH 16384
#define HID   512
#define KDIM  1024   // INPUT + HIDDEN
#define BM    64     // batch rows per block
#define NSTEP 16     // K-steps of 64

typedef __bf16 bf16x8 __attribute__((ext_vector_type(8)));
typedef float  floatx4 __attribute__((ext_vector_type(4)));

__device__ __forceinline__ float fast_sigmoid(float x) {
  return 1.0f / (1.0f + __expf(-x));
}
__device__ __forceinline__ float fast_tanh(float x) {
  float e = __expf(-2.0f * fabsf(x));
  float t = (1.0f - e) / (1.0f + e);
  return x >= 0.0f ? t : -t;
}
__device__ __forceinline__ u16 f2bf(float f) {
  return __builtin_bit_cast(u16, __float2bfloat16(f));
}

// Raw barrier: only LDS ordering needed at the step boundary (bf16 tile
// ds_writes -> other waves' ds_reads next step). Global loads land in
// registers only; they stay in flight across the barrier (compiler inserts
// counted vmcnt at first use). Verified safe in R2 (passed).
__device__ __forceinline__ void barrier_lds_only() {
  asm volatile("s_waitcnt lgkmcnt(0)" ::: "memory");
  __builtin_amdgcn_s_barrier();
  __builtin_amdgcn_sched_barrier(0);
}

// ---------- pre-pass: W only ----------
// Wf: MFMA-FRAGMENT-MAJOR weights so B-loads are one coalesced dwordx4:
//   elem (gate g, per-gate col n, k) at
//   (((g*32 + n/16)*32 + k/32)*64 + ((k>>3)&3)*16 + (n&15))*8 + (k&7)
__global__ __launch_bounds__(256) void pack_w_kernel(
    const float* __restrict__ Wi, const float* __restrict__ Wf_,
    const float* __restrict__ Wo, const float* __restrict__ Wg,
    u16* __restrict__ Wf) {
  int grow = blockIdx.x;                  // 0..2047, order [Wi|Wf|Wo|Wg]
  int k = threadIdx.x * 4;
  int g = grow >> 9;
  int n = grow & (HID - 1);
  const float* s = g == 0 ? Wi : g == 1 ? Wf_ : g == 2 ? Wo : Wg;
  float4 v = *(const float4*)(s + (size_t)n * KDIM + k);
  ushort4 o;
  o.x = f2bf(v.x); o.y = f2bf(v.y); o.z = f2bf(v.z); o.w = f2bf(v.w);
  size_t d = ((size_t)((g * 32 + (n >> 4)) * 32 + (k >> 5)) * 64 +
              ((k >> 3) & 3) * 16 + (n & 15)) * 8 + (k & 7);
  *(ushort4*)(Wf + d) = o;
}

// ---------- main fused GEMM + LSTM epilogue ----------
// RESIDENCY FIX (R5): 512-thread blocks at ~252 unified regs/wave = 1
// block/CU resident (measured Occupancy ~20% across R1-R4). Retile to
// 4-wave/256-thread blocks, BM=64, each wave owning TWO 16-col n-tiles:
// per-wave work identical to R1's verified wave (64 MFMA/step, acc=128),
// but per-block register footprint is 4x smaller -> ~7-8 blocks/CU
// (LDS 16KB/block caps at 10). Independent barrier domains anti-phase,
// so staging of one block overlaps MFMA of others.
// Schedule = R1's proven 2-phase: ldX(S+1) issue-early, compute(buf),
// loadB(S+1) after last use, cvt+swizzled-write, lds-only barrier.
// LDS swizzle (verified, 0 conflicts): write lane-linear, swizzle on the
// GLOBAL source chunk c=(lane&7)^(row&7); compute reads chunk
// (kk*4+lquad)^(lrow&7).
__global__ __launch_bounds__(256, 4) void lstm_gemm_kernel(
    const float* __restrict__ input_, const float* __restrict__ prev_h,
    const u16* __restrict__ Wf,
    const float* __restrict__ Bi, const float* __restrict__ Bf,
    const float* __restrict__ Bo, const float* __restrict__ Bg,
    const float* __restrict__ prevC, float* __restrict__ out) {
  __shared__ u16 lds[2][4096];   // per buf: 64 rows x 64 elems = 8 KB

  const int tid = threadIdx.x;
  const int wave = tid >> 6, lane = tid & 63;
  const int lrow = lane & 15, lquad = lane >> 4;
  const int m_block = blockIdx.y * BM;
  const int ntg0 = blockIdx.x * 8 + wave * 2;   // wave owns tiles ntg0, ntg0+1

  // Staging: instr i (0,1) covers rows li*8+(lane>>3), li = wave*2+i.
  // Lane fetches logical chunk (lane&7)^(row&7), writes lane-linear.
  const int swzf = ((lane & 7) ^ ((lane >> 3) & 7)) * 8;  // in elements
  const float* xh[2];   // prev_h row base (+swizzle), K-steps 0..7
  const float* xi[2];   // input_ row base (+swizzle), K-steps 8..15
  int lp[2];            // LDS elem offset this lane writes
#pragma unroll
  for (int i = 0; i < 2; ++i) {
    int li = wave * 2 + i;
    int row = m_block + li * 8 + (lane >> 3);
    xh[i] = prev_h + (size_t)row * HID + swzf;
    xi[i] = input_ + (size_t)row * HID + swzf;
    lp[i] = li * 512 + lane * 8;
  }

  floatx4 acc[4][2][4];   // [gate][n-tile][m-tile] = 128 (AGPRs)
#pragma unroll
  for (int g = 0; g < 4; ++g)
#pragma unroll
    for (int nt = 0; nt < 2; ++nt)
#pragma unroll
      for (int mt = 0; mt < 4; ++mt)
        acc[g][nt][mt] = (floatx4){0.f, 0.f, 0.f, 0.f};

  float4 r[2][2];      // in-flight fp32 X for next step (16 VGPRs)
  auto ldX = [&](int S) {
#pragma unroll
    for (int i = 0; i < 2; ++i) {
      const float* base = (S < 8) ? (xh[i] + S * 64) : (xi[i] + (S - 8) * 64);
      r[i][0] = *(const float4*)(base);
      r[i][1] = *(const float4*)(base + 4);
    }
  };

  auto cvtWrite = [&](int buf) {
#pragma unroll
    for (int i = 0; i < 2; ++i) {
      union { u16 u[8]; bf16x8 v; } t;
      t.u[0] = f2bf(r[i][0].x); t.u[1] = f2bf(r[i][0].y);
      t.u[2] = f2bf(r[i][0].z); t.u[3] = f2bf(r[i][0].w);
      t.u[4] = f2bf(r[i][1].x); t.u[5] = f2bf(r[i][1].y);
      t.u[6] = f2bf(r[i][1].z); t.u[7] = f2bf(r[i][1].w);
      *(bf16x8*)(&lds[buf][lp[i]]) = t.v;   // 16B-aligned, conflict-free
    }
  };

  bf16x8 b[2][2][4];   // [kk][n-tile][gate] single buffer (32 VGPRs)
  auto loadB = [&](int S) {
#pragma unroll
    for (int kk = 0; kk < 2; ++kk)
#pragma unroll
      for (int nt = 0; nt < 2; ++nt)
#pragma unroll
        for (int g = 0; g < 4; ++g)
          b[kk][nt][g] = *(const bf16x8*)(
              Wf + (((size_t)(g * 32 + ntg0 + nt) * 32 + (S * 2 + kk)) << 9) +
              lane * 8);
  };

  auto compute = [&](int buf) {
    const u16* LA = &lds[buf][0];
    __builtin_amdgcn_s_setprio(1);
#pragma unroll
    for (int kk = 0; kk < 2; ++kk) {
#pragma unroll
      for (int mt = 0; mt < 4; ++mt) {
        bf16x8 a = *(const bf16x8*)
            &LA[(mt * 16 + lrow) * 64 + (((kk * 4 + lquad) ^ (lrow & 7)) * 8)];
#pragma unroll
        for (int nt = 0; nt < 2; ++nt)
#pragma unroll
          for (int g = 0; g < 4; ++g)
            acc[g][nt][mt] = __builtin_amdgcn_mfma_f32_16x16x32_bf16(
                a, b[kk][nt][g], acc[g][nt][mt], 0, 0, 0);
      }
    }
    __builtin_amdgcn_s_setprio(0);
  };

  // ---- prologue ----
  loadB(0);
  ldX(0);
  cvtWrite(0);
  barrier_lds_only();

  // ---- main loop: 2-phase, one barrier per K-step ----
  // iter S reads buf=S&1, writes buf^1 (readers of buf^1 retired at the
  // iter S-1 barrier's lgkmcnt(0)).
  for (int S = 0; S < NSTEP; ++S) {
    const int buf = S & 1;
    if (S + 1 < NSTEP) ldX(S + 1);     // issue early
    compute(buf);
    if (S + 1 < NSTEP) {
      loadB(S + 1);                    // after b's last use (WAR ok)
      cvtWrite(buf ^ 1);               // waits only on ldX's 4 loads
      barrier_lds_only();
    }
  }

  // ---- epilogue. C layout (verified): col=lane&15, row=lquad*4+reg ----
  float* outH = out;
  float* outC = out + (size_t)BATCH * HID;
#pragma unroll
  for (int nt = 0; nt < 2; ++nt) {
    const int j = (ntg0 + nt) * 16 + lrow;     // 0..511
    const float vbi = Bi[j], vbf = Bf[j], vbo = Bo[j], vbg = Bg[j];
#pragma unroll
    for (int mt = 0; mt < 4; ++mt) {
      int rowb = m_block + mt * 16 + lquad * 4;
#pragma unroll
      for (int rg = 0; rg < 4; ++rg) {
        int row = rowb + rg;
        float gi = fast_sigmoid(acc[0][nt][mt][rg] + vbi);
        float gf = fast_sigmoid(acc[1][nt][mt][rg] + vbf);
        float go = fast_sigmoid(acc[2][nt][mt][rg] + vbo);
        float gg = fast_tanh(acc[3][nt][mt][rg] + vbg);
        float c = gf * prevC[row * HID + j] + gi * gg;
        float h = fast_tanh(c) * go;
        outH[row * HID + j] = h;
        outC[row * HID + j] = c;
      }
    }
  }
}

// ---------- slow fallback if ws too small (correctness insurance) ----------
__global__ void lstm_fallback_kernel(
    const float* __restrict__ input_, const float* __restrict__ prev_h,
    const float* __restrict__ prevC,
    const float* __restrict__ Wi, const float* __restrict__ Bi,
    const float* __restrict__ Wf, const float* __restrict__ Bf,
    const float* __restrict__ Wo, const float* __restrict__ Bo,
    const float* __restrict__ Wg, const float* __restrict__ Bg,
    float* __restrict__ out) {
  int idx = blockIdx.x * blockDim.x + threadIdx.x;
  int b = idx / HID, j = idx % HID;
  if (b >= BATCH) return;
  float si = 0.f, sf = 0.f, so = 0.f, sg = 0.f;
  for (int k = 0; k < KDIM; ++k) {
    float x = (k < HID) ? prev_h[b * HID + k] : input_[b * HID + (k - HID)];
    si += x * Wi[j * KDIM + k];
    sf += x * Wf[j * KDIM + k];
    so += x * Wo[j * KDIM + k];
    sg += x * Wg[j * KDIM + k];
  }
  float gi = fast_sigmoid(si + Bi[j]);
  float gf = fast_sigmoid(sf + Bf[j]);
  float go = fast_sigmoid(so + Bo[j]);
  float gg = fast_tanh(sg + Bg[j]);
  float c = gf * prevC[b * HID + j] + gi * gg;
  out[b * HID + j] = fast_tanh(c) * go;
  out[(size_t)BATCH * HID + b * HID + j] = c;
}

extern "C" void kernel_launch(void* const* d_in, const int* in_sizes, int n_in,
                              void* d_out, int out_size, void* d_ws, size_t ws_size,
                              hipStream_t stream) {
  const float* input_ = (const float*)d_in[0];
  const float* prev_h = (const float*)d_in[1];
  const float* prev_c = (const float*)d_in[2];
  const float* W_i = (const float*)d_in[3];
  const float* b_i = (const float*)d_in[4];
  const float* W_f = (const float*)d_in[5];
  const float* b_f = (const float*)d_in[6];
  const float* W_g = (const float*)d_in[7];
  const float* b_g = (const float*)d_in[8];
  const float* W_o = (const float*)d_in[9];
  const float* b_o = (const float*)d_in[10];
  float* out = (float*)d_out;

  const size_t ws_needed = (size_t)4 * HID * KDIM * sizeof(u16);   // 4 MB

  if (ws_size < ws_needed) {
    int total = BATCH * HID;
    lstm_fallback_kernel<<<(total + 255) / 256, 256, 0, stream>>>(
        input_, prev_h, prev_c, W_i, b_i, W_f, b_f, W_o, b_o, W_g, b_g, out);
    return;
  }

  u16* Wfp = (u16*)d_ws;                      // fragment-major bf16 W, 4 MB

  pack_w_kernel<<<4 * HID, 256, 0, stream>>>(W_i, W_f, W_o, W_g, Wfp);

  // grid.x = 4 n-blocks (8 tiles each), grid.y = 256 m-blocks of 64 rows.
  // 1024 blocks x 256 thr; ~7-8 blocks/CU resident (regs ~250/wave, LDS 16KB).
  dim3 grid(4, BATCH / BM);
  lstm_gemm_kernel<<<grid, 256, 0, stream>>>(input_, prev_h, Wfp,
                                             b_i, b_f, b_o, b_g, prev_c, out);
}

// Round 6
// 227.447 us; speedup vs baseline: 5.1423x; 5.1423x over previous
//
#include <hip/hip_runtime.h>
#include <hip/hip_bf16.h>
#include <math.h>

typedef unsigned short u16;

#define BATCH 16384
#define HID   512
#define KDIM  1024   // INPUT + HIDDEN
#define BM    128    // batch rows per block
#define NSTEP 16     // K-steps of 64
#define NTILE 8      // barrier tiles of 128 k (2 K-steps)

typedef __bf16 bf16x8 __attribute__((ext_vector_type(8)));
typedef float  floatx4 __attribute__((ext_vector_type(4)));

__device__ __forceinline__ float fast_sigmoid(float x) {
  return 1.0f / (1.0f + __expf(-x));
}
__device__ __forceinline__ float fast_tanh(float x) {
  float e = __expf(-2.0f * fabsf(x));
  float t = (1.0f - e) / (1.0f + e);
  return x >= 0.0f ? t : -t;
}
__device__ __forceinline__ u16 f2bf(float f) {
  return __builtin_bit_cast(u16, __float2bfloat16(f));
}

// Raw barrier: only LDS ordering is needed at the tile boundary (bf16
// ds_writes -> other waves' ds_reads next tile). Global loads land in
// registers only; they stay in flight across the barrier (compiler inserts
// counted vmcnt at first use). Verified safe in R2 (passed).
__device__ __forceinline__ void barrier_lds_only() {
  asm volatile("s_waitcnt lgkmcnt(0)" ::: "memory");
  __builtin_amdgcn_s_barrier();
  __builtin_amdgcn_sched_barrier(0);
}

// ---------- pre-pass: W only ----------
// Wf: MFMA-FRAGMENT-MAJOR weights so B-loads are one coalesced dwordx4:
//   elem (gate g, per-gate col n, k) at
//   (((g*32 + n/16)*32 + k/32)*64 + ((k>>3)&3)*16 + (n&15))*8 + (k&7)
__global__ __launch_bounds__(256) void pack_w_kernel(
    const float* __restrict__ Wi, const float* __restrict__ Wf_,
    const float* __restrict__ Wo, const float* __restrict__ Wg,
    u16* __restrict__ Wf) {
  int grow = blockIdx.x;                  // 0..2047, order [Wi|Wf|Wo|Wg]
  int k = threadIdx.x * 4;
  int g = grow >> 9;
  int n = grow & (HID - 1);
  const float* s = g == 0 ? Wi : g == 1 ? Wf_ : g == 2 ? Wo : Wg;
  float4 v = *(const float4*)(s + (size_t)n * KDIM + k);
  ushort4 o;
  o.x = f2bf(v.x); o.y = f2bf(v.y); o.z = f2bf(v.z); o.w = f2bf(v.w);
  size_t d = ((size_t)((g * 32 + (n >> 4)) * 32 + (k >> 5)) * 64 +
              ((k >> 3) & 3) * 16 + (n & 15)) * 8 + (k & 7);
  *(ushort4*)(Wf + d) = o;
}

// ---------- main fused GEMM + LSTM epilogue ----------
// R6: BK=128 — two K-steps per barrier tile. Same verified R1/R2 structure
// (reg-staged fp32->bf16 X, single-buffer register B, zero-conflict LDS
// swizzle: write lane-linear, swizzle applied to the GLOBAL source chunk
// c=(lane&7)^(row&7); compute reads chunk (kk*4+lquad)^(lrow&7)).
// Each LDS buffer now holds TWO independent 64-col halves at the old layout
// (offsets 0 / 8192 elems); barriers drop 16 -> 8+1. Register footprint
// unchanged (r and b reused across the two sub-steps): no spill risk
// (R5 lesson: never cap below acc+working set).
__global__ __launch_bounds__(512, 2) void lstm_gemm_kernel(
    const float* __restrict__ input_, const float* __restrict__ prev_h,
    const u16* __restrict__ Wf,
    const float* __restrict__ Bi, const float* __restrict__ Bf,
    const float* __restrict__ Bo, const float* __restrict__ Bg,
    const float* __restrict__ prevC, float* __restrict__ out) {
  __shared__ u16 lds[2][16384];  // per buf: 2 halves x (128 rows x 64) = 32 KB

  const int tid = threadIdx.x;
  const int wave = tid >> 6, lane = tid & 63;
  const int lrow = lane & 15, lquad = lane >> 4;
  const int m_block = blockIdx.x * BM;
  const int ntg = blockIdx.y * 8 + wave;   // global per-gate 16-col tile id

  // Staging: instr i (0,1) covers rows li*8+(lane>>3), li = wave*2+i.
  // Lane fetches logical chunk (lane&7)^(row&7), writes lane-linear.
  const int swzf = ((lane & 7) ^ ((lane >> 3) & 7)) * 8;  // in elements
  const float* xh[2];   // prev_h row base (+swizzle), K-steps 0..7
  const float* xi[2];   // input_ row base (+swizzle), K-steps 8..15
  int lp[2];            // LDS elem offset this lane writes (within a half)
#pragma unroll
  for (int i = 0; i < 2; ++i) {
    int li = wave * 2 + i;
    int row = m_block + li * 8 + (lane >> 3);
    xh[i] = prev_h + (size_t)row * HID + swzf;
    xi[i] = input_ + (size_t)row * HID + swzf;
    lp[i] = li * 512 + lane * 8;
  }

  floatx4 acc[4][8];   // [gate][m-tile]  (AGPRs, 128)
#pragma unroll
  for (int g = 0; g < 4; ++g)
#pragma unroll
    for (int mt = 0; mt < 8; ++mt)
      acc[g][mt] = (floatx4){0.f, 0.f, 0.f, 0.f};

  float4 r[2][2];      // in-flight fp32 X for ONE future step (16 VGPRs)
  auto ldX = [&](int S) {
#pragma unroll
    for (int i = 0; i < 2; ++i) {
      const float* base = (S < 8) ? (xh[i] + S * 64) : (xi[i] + (S - 8) * 64);
      r[i][0] = *(const float4*)(base);
      r[i][1] = *(const float4*)(base + 4);
    }
  };

  // write r into half h of buf
  auto cvtWrite = [&](int buf, int h) {
    u16* L = &lds[buf][h * 8192];
#pragma unroll
    for (int i = 0; i < 2; ++i) {
      union { u16 u[8]; bf16x8 v; } t;
      t.u[0] = f2bf(r[i][0].x); t.u[1] = f2bf(r[i][0].y);
      t.u[2] = f2bf(r[i][0].z); t.u[3] = f2bf(r[i][0].w);
      t.u[4] = f2bf(r[i][1].x); t.u[5] = f2bf(r[i][1].y);
      t.u[6] = f2bf(r[i][1].z); t.u[7] = f2bf(r[i][1].w);
      *(bf16x8*)(&L[lp[i]]) = t.v;   // 16B-aligned, conflict-free
    }
  };

  bf16x8 b[2][4];      // single B buffer for ONE K-step (32 VGPRs)
  auto loadB = [&](int S) {
#pragma unroll
    for (int kk = 0; kk < 2; ++kk)
#pragma unroll
      for (int g = 0; g < 4; ++g)
        b[kk][g] = *(const bf16x8*)(
            Wf + (((size_t)(g * 32 + ntg) * 32 + (S * 2 + kk)) << 9) +
            lane * 8);
  };

  // compute one K-step from half h of buf
  auto compute = [&](int buf, int h) {
    const u16* LA = &lds[buf][h * 8192];
    __builtin_amdgcn_s_setprio(1);
#pragma unroll
    for (int kk = 0; kk < 2; ++kk) {
#pragma unroll
      for (int mt = 0; mt < 8; ++mt) {
        bf16x8 a = *(const bf16x8*)
            &LA[(mt * 16 + lrow) * 64 + (((kk * 4 + lquad) ^ (lrow & 7)) * 8)];
#pragma unroll
        for (int g = 0; g < 4; ++g)
          acc[g][mt] = __builtin_amdgcn_mfma_f32_16x16x32_bf16(
              a, b[kk][g], acc[g][mt], 0, 0, 0);
      }
    }
    __builtin_amdgcn_s_setprio(0);
  };

  // ---- prologue: fill buf0 with steps 0,1; b=B(0); r=X(2) ----
  loadB(0);
  ldX(0); cvtWrite(0, 0);
  ldX(1); cvtWrite(0, 1);
  ldX(2);
  barrier_lds_only();

  // ---- main loop: one barrier per 128-k tile ----
  // Invariant at top of tile T: buf=T&1 holds steps 2T,2T+1; b=B(2T);
  // r=X(2T+2). buf^1's readers retired at the previous barrier.
  for (int T = 0; T < NTILE; ++T) {
    const int buf = T & 1;
    compute(buf, 0);                 // step 2T, uses b=B(2T)
    loadB(2 * T + 1);                // after b's last use (WAR ok)
    if (T < NTILE - 1) {
      cvtWrite(buf ^ 1, 0);          // X(2T+2) -> next buf half0
      ldX(2 * T + 3);
    }
    compute(buf, 1);                 // step 2T+1, uses b=B(2T+1)
    if (T < NTILE - 1) {
      loadB(2 * T + 2);
      cvtWrite(buf ^ 1, 1);          // X(2T+3) -> next buf half1
      if (T < NTILE - 2) ldX(2 * T + 4);
      barrier_lds_only();
    }
  }

  // ---- epilogue. C layout (verified): col=lane&15, row=lquad*4+reg ----
  const int j = ntg * 16 + lrow;        // 0..511
  const float vbi = Bi[j], vbf = Bf[j], vbo = Bo[j], vbg = Bg[j];
  float* outH = out;
  float* outC = out + (size_t)BATCH * HID;
#pragma unroll
  for (int mt = 0; mt < 8; ++mt) {
    int rowb = m_block + mt * 16 + lquad * 4;
#pragma unroll
    for (int rg = 0; rg < 4; ++rg) {
      int row = rowb + rg;
      float gi = fast_sigmoid(acc[0][mt][rg] + vbi);
      float gf = fast_sigmoid(acc[1][mt][rg] + vbf);
      float go = fast_sigmoid(acc[2][mt][rg] + vbo);
      float gg = fast_tanh(acc[3][mt][rg] + vbg);
      float c = gf * prevC[row * HID + j] + gi * gg;
      float h = fast_tanh(c) * go;
      outH[row * HID + j] = h;
      outC[row * HID + j] = c;
    }
  }
}

// ---------- slow fallback if ws too small (correctness insurance) ----------
__global__ void lstm_fallback_kernel(
    const float* __restrict__ input_, const float* __restrict__ prev_h,
    const float* __restrict__ prevC,
    const float* __restrict__ Wi, const float* __restrict__ Bi,
    const float* __restrict__ Wf, const float* __restrict__ Bf,
    const float* __restrict__ Wo, const float* __restrict__ Bo,
    const float* __restrict__ Wg, const float* __restrict__ Bg,
    float* __restrict__ out) {
  int idx = blockIdx.x * blockDim.x + threadIdx.x;
  int b = idx / HID, j = idx % HID;
  if (b >= BATCH) return;
  float si = 0.f, sf = 0.f, so = 0.f, sg = 0.f;
  for (int k = 0; k < KDIM; ++k) {
    float x = (k < HID) ? prev_h[b * HID + k] : input_[b * HID + (k - HID)];
    si += x * Wi[j * KDIM + k];
    sf += x * Wf[j * KDIM + k];
    so += x * Wo[j * KDIM + k];
    sg += x * Wg[j * KDIM + k];
  }
  float gi = fast_sigmoid(si + Bi[j]);
  float gf = fast_sigmoid(sf + Bf[j]);
  float go = fast_sigmoid(so + Bo[j]);
  float gg = fast_tanh(sg + Bg[j]);
  float c = gf * prevC[b * HID + j] + gi * gg;
  out[b * HID + j] = fast_tanh(c) * go;
  out[(size_t)BATCH * HID + b * HID + j] = c;
}

extern "C" void kernel_launch(void* const* d_in, const int* in_sizes, int n_in,
                              void* d_out, int out_size, void* d_ws, size_t ws_size,
                              hipStream_t stream) {
  const float* input_ = (const float*)d_in[0];
  const float* prev_h = (const float*)d_in[1];
  const float* prev_c = (const float*)d_in[2];
  const float* W_i = (const float*)d_in[3];
  const float* b_i = (const float*)d_in[4];
  const float* W_f = (const float*)d_in[5];
  const float* b_f = (const float*)d_in[6];
  const float* W_g = (const float*)d_in[7];
  const float* b_g = (const float*)d_in[8];
  const float* W_o = (const float*)d_in[9];
  const float* b_o = (const float*)d_in[10];
  float* out = (float*)d_out;

  const size_t ws_needed = (size_t)4 * HID * KDIM * sizeof(u16);   // 4 MB

  if (ws_size < ws_needed) {
    int total = BATCH * HID;
    lstm_fallback_kernel<<<(total + 255) / 256, 256, 0, stream>>>(
        input_, prev_h, prev_c, W_i, b_i, W_f, b_f, W_o, b_o, W_g, b_g, out);
    return;
  }

  u16* Wfp = (u16*)d_ws;                      // fragment-major bf16 W, 4 MB

  pack_w_kernel<<<4 * HID, 256, 0, stream>>>(W_i, W_f, W_o, W_g, Wfp);

  dim3 grid(BATCH / BM, HID / 128);           // 128 x 4 = 512 blocks
  lstm_gemm_kernel<<<grid, 512, 0, stream>>>(input_, prev_h, Wfp,
                                             b_i, b_f, b_o, b_g, prev_c, out);
}